// Round 1
// baseline (214.523 us; speedup 1.0000x reference)
//
#include <hip/hip_runtime.h>
#include <hip/hip_bf16.h>
#include <math.h>

#define B 8
#define S 2048
#define IN_DIM 8
#define EMB 512
#define HEADS 8
#define HDIM 64
#define HALF 256
#define NCLS 3

// workspace layout (float offsets)
#define WS_KQ    0            // [B][HEADS][EMB]        = 32768
#define WS_COEF1 32768        // [B][HEADS][12]         = 768   (a[0..7], c0, c1)
#define WS_SC    33536        // [B][HEADS][S]          = 131072 (scores -> attn in place)
#define WS_COEF2 164608       // [B][HEADS][12]         = 768   (fa[0..7], ta)
#define WS_SPART 165376       // [B][16][HEADS][HALF]   = 524288
// total 689664 floats = 2.76 MB

// K1: per-b: x_last -> q -> kq[h][j] -> per-head coefficients
__global__ __launch_bounds__(512) void k_prep(
    const float* __restrict__ feat, const float* __restrict__ ts,
    const float* __restrict__ Wf, const float* __restrict__ bf,
    const float* __restrict__ Wl, const float* __restrict__ bl,
    const float* __restrict__ Wp, const float* __restrict__ bp,
    const float* __restrict__ Wq, const float* __restrict__ bq,
    const float* __restrict__ Wk, const float* __restrict__ bk,
    float* __restrict__ ws)
{
    const int b = blockIdx.x;
    const int tid = threadIdx.x;
    __shared__ float xl[EMB];
    __shared__ float q[EMB];
    __shared__ float kq[HEADS][EMB];

    // x at last position
    {
        const float tl = ts[b*S + (S-1)];
        float acc = bf[tid];
        #pragma unroll
        for (int i = 0; i < IN_DIM; ++i)
            acc += feat[(b*S + (S-1))*IN_DIM + i] * Wf[i*EMB + tid];
        float te;
        if (tid < HALF) te = tl*Wl[tid] + bl[tid];
        else            te = __sinf(tl*Wp[tid-HALF] + bp[tid-HALF]);
        xl[tid] = acc + te;
    }
    __syncthreads();
    // q = x_last @ Wq + bq
    {
        float acc = bq[tid];
        #pragma unroll 8
        for (int j = 0; j < EMB; ++j)
            acc += xl[j]*Wq[j*EMB + tid];
        q[tid] = acc;
    }
    __syncthreads();
    // kq[h][j] = sum_d Wk[j, h*64+d] * q[h*64+d]
    {
        const float* wkrow = Wk + tid*EMB;
        #pragma unroll
        for (int h = 0; h < HEADS; ++h) {
            float acc = 0.f;
            #pragma unroll 16
            for (int d = 0; d < HDIM; ++d)
                acc += wkrow[h*HDIM + d]*q[h*HDIM + d];
            kq[h][tid] = acc;
            ws[WS_KQ + (b*HEADS + h)*EMB + tid] = acc;
        }
    }
    __syncthreads();
    // per-head coefficients: a[i] = Wf[i,:].kq ; c0 = bf.kq + bl.kq_lo + q_h.bk_h ; c1 = Wl.kq_lo
    {
        const int h = tid >> 6, lane = tid & 63;
        float a[IN_DIM] = {0.f,0.f,0.f,0.f,0.f,0.f,0.f,0.f};
        float c0 = 0.f, c1 = 0.f;
        for (int e = lane; e < EMB; e += 64) {
            const float kv = kq[h][e];
            #pragma unroll
            for (int i = 0; i < IN_DIM; ++i) a[i] += Wf[i*EMB + e]*kv;
            c0 += bf[e]*kv;
            if (e < HALF) { c0 += bl[e]*kv; c1 += Wl[e]*kv; }
        }
        c0 += bk[h*HDIM + lane]*q[h*HDIM + lane];
        #pragma unroll
        for (int off = 32; off >= 1; off >>= 1) {
            #pragma unroll
            for (int i = 0; i < IN_DIM; ++i) a[i] += __shfl_xor(a[i], off, 64);
            c0 += __shfl_xor(c0, off, 64);
            c1 += __shfl_xor(c1, off, 64);
        }
        if (lane == 0) {
            float* cp = ws + WS_COEF1 + (b*HEADS + h)*12;
            #pragma unroll
            for (int i = 0; i < IN_DIM; ++i) cp[i] = a[i];
            cp[8] = c0; cp[9] = c1;
        }
    }
}

// K2: scores[b,h,t] = (f_t.a + c0 + t*c1 + sum_j sin(t*Wp[j]+bp[j])*kq_hi[h][j]) / 8 * decay
__global__ __launch_bounds__(256) void k_scores(
    const float* __restrict__ feat, const float* __restrict__ ts,
    const float* __restrict__ Wp, const float* __restrict__ bp,
    const float* __restrict__ tdp, float* __restrict__ ws)
{
    const int b = blockIdx.y;
    const int chunk = blockIdx.x;        // 32 chunks x 64 t
    const int tid = threadIdx.x;
    __shared__ __align__(16) float kqh[HEADS][HALF];
    __shared__ float wp_l[HALF], bp_l[HALF];
    __shared__ float cf[HEADS*12];

    for (int idx = tid; idx < HEADS*HALF; idx += 256) {
        const int h = idx >> 8, j = idx & 255;
        kqh[h][j] = ws[WS_KQ + (b*HEADS + h)*EMB + HALF + j];
    }
    if (tid < HALF) { wp_l[tid] = Wp[tid]; bp_l[tid] = bp[tid]; }
    if (tid < HEADS*12) cf[tid] = ws[WS_COEF1 + b*HEADS*12 + tid];
    __syncthreads();

    const int jq = tid & 3;                  // 4-way split over j
    const int t = chunk*64 + (tid >> 2);
    const float tv = ts[b*S + t];

    float acc[HEADS];
    #pragma unroll
    for (int h = 0; h < HEADS; ++h) acc[h] = 0.f;

    for (int jj = 0; jj < 64; jj += 4) {
        const int j0 = jq*64 + jj;
        const float s0 = __sinf(tv*wp_l[j0+0] + bp_l[j0+0]);
        const float s1 = __sinf(tv*wp_l[j0+1] + bp_l[j0+1]);
        const float s2 = __sinf(tv*wp_l[j0+2] + bp_l[j0+2]);
        const float s3 = __sinf(tv*wp_l[j0+3] + bp_l[j0+3]);
        #pragma unroll
        for (int h = 0; h < HEADS; ++h) {
            const float4 kv = *(const float4*)&kqh[h][j0];
            acc[h] += s0*kv.x + s1*kv.y + s2*kv.z + s3*kv.w;
        }
    }
    #pragma unroll
    for (int h = 0; h < HEADS; ++h) {
        acc[h] += __shfl_xor(acc[h], 1, 64);
        acc[h] += __shfl_xor(acc[h], 2, 64);
    }
    if (jq == 0) {
        const float tl = ts[b*S + (S-1)];
        const float dec = __expf(-tdp[0]*fabsf(tl - tv));
        float f[IN_DIM];
        #pragma unroll
        for (int i = 0; i < IN_DIM; ++i) f[i] = feat[(b*S + t)*IN_DIM + i];
        #pragma unroll
        for (int h = 0; h < HEADS; ++h) {
            const float* c = cf + h*12;
            float base = c[8] + tv*c[9];
            #pragma unroll
            for (int i = 0; i < IN_DIM; ++i) base += f[i]*c[i];
            ws[WS_SC + (b*HEADS + h)*S + t] = (base + acc[h])*0.125f*dec;
        }
    }
}

// K3: per (b,h): softmax over 2048 scores (in place) + fa[i]=sum attn*f, ta=sum attn*t
__global__ __launch_bounds__(256) void k_softmax(
    const float* __restrict__ feat, const float* __restrict__ ts,
    float* __restrict__ ws)
{
    const int bh = blockIdx.x;
    const int b = bh >> 3;
    const int tid = threadIdx.x;
    float* row = ws + WS_SC + bh*S;

    float v[8];
    float mx = -1e30f;
    #pragma unroll
    for (int i = 0; i < 8; ++i) { v[i] = row[tid + 256*i]; mx = fmaxf(mx, v[i]); }
    #pragma unroll
    for (int off = 32; off >= 1; off >>= 1) mx = fmaxf(mx, __shfl_xor(mx, off, 64));
    __shared__ float red[4];
    const int wid = tid >> 6, lane = tid & 63;
    if (lane == 0) red[wid] = mx;
    __syncthreads();
    mx = fmaxf(fmaxf(red[0], red[1]), fmaxf(red[2], red[3]));

    float sm = 0.f;
    #pragma unroll
    for (int i = 0; i < 8; ++i) { v[i] = __expf(v[i] - mx); sm += v[i]; }
    #pragma unroll
    for (int off = 32; off >= 1; off >>= 1) sm += __shfl_xor(sm, off, 64);
    __syncthreads();
    if (lane == 0) red[wid] = sm;
    __syncthreads();
    sm = red[0] + red[1] + red[2] + red[3];
    const float inv = 1.f/sm;

    float fa[IN_DIM] = {0.f,0.f,0.f,0.f,0.f,0.f,0.f,0.f};
    float ta = 0.f;
    #pragma unroll
    for (int i = 0; i < 8; ++i) {
        const int t = tid + 256*i;
        const float a_ = v[i]*inv;
        row[t] = a_;
        ta += a_*ts[b*S + t];
        const float4 f0 = *(const float4*)&feat[(b*S + t)*IN_DIM];
        const float4 f1 = *(const float4*)&feat[(b*S + t)*IN_DIM + 4];
        fa[0] += a_*f0.x; fa[1] += a_*f0.y; fa[2] += a_*f0.z; fa[3] += a_*f0.w;
        fa[4] += a_*f1.x; fa[5] += a_*f1.y; fa[6] += a_*f1.z; fa[7] += a_*f1.w;
    }
    #pragma unroll
    for (int off = 32; off >= 1; off >>= 1) {
        #pragma unroll
        for (int k = 0; k < IN_DIM; ++k) fa[k] += __shfl_xor(fa[k], off, 64);
        ta += __shfl_xor(ta, off, 64);
    }
    __shared__ float red9[4][12];
    if (lane == 0) {
        #pragma unroll
        for (int k = 0; k < IN_DIM; ++k) red9[wid][k] = fa[k];
        red9[wid][8] = ta;
    }
    __syncthreads();
    if (tid < 9) {
        const float sv = red9[0][tid]+red9[1][tid]+red9[2][tid]+red9[3][tid];
        ws[WS_COEF2 + bh*12 + tid] = sv;
    }
}

// K4: S_partial[b,chunk,h,j] = sum_{t in chunk} attn[b,h,t]*sin(t*Wp[j]+bp[j])
__global__ __launch_bounds__(256) void k_sweight(
    const float* __restrict__ ts, const float* __restrict__ Wp, const float* __restrict__ bp,
    float* __restrict__ ws)
{
    const int b = blockIdx.y;
    const int chunk = blockIdx.x;   // 16 chunks x 128 t
    const int tid = threadIdx.x;    // = j
    __shared__ __align__(16) float at_l[HEADS][128];
    __shared__ float tv_l[128];
    for (int idx = tid; idx < HEADS*128; idx += 256) {
        const int h = idx >> 7, tt = idx & 127;
        at_l[h][tt] = ws[WS_SC + (b*HEADS + h)*S + chunk*128 + tt];
    }
    if (tid < 128) tv_l[tid] = ts[b*S + chunk*128 + tid];
    __syncthreads();
    const float wj = Wp[tid], bj = bp[tid];
    float acc[HEADS] = {0.f,0.f,0.f,0.f,0.f,0.f,0.f,0.f};
    for (int tt = 0; tt < 128; tt += 4) {
        const float s0 = __sinf(tv_l[tt+0]*wj + bj);
        const float s1 = __sinf(tv_l[tt+1]*wj + bj);
        const float s2 = __sinf(tv_l[tt+2]*wj + bj);
        const float s3 = __sinf(tv_l[tt+3]*wj + bj);
        #pragma unroll
        for (int h = 0; h < HEADS; ++h) {
            const float4 av = *(const float4*)&at_l[h][tt];
            acc[h] += s0*av.x + s1*av.y + s2*av.z + s3*av.w;
        }
    }
    #pragma unroll
    for (int h = 0; h < HEADS; ++h)
        ws[WS_SPART + ((b*16 + chunk)*HEADS + h)*HALF + tid] = acc[h];
}

// K5: per b: assemble weighted_x, then GEMV chain Wv -> Wo -> W1(relu) -> W2 -> logits
__global__ __launch_bounds__(256) void k_final(
    const float* __restrict__ Wf, const float* __restrict__ bf,
    const float* __restrict__ Wl, const float* __restrict__ bl,
    const float* __restrict__ Wv, const float* __restrict__ bv,
    const float* __restrict__ Wo, const float* __restrict__ bo,
    const float* __restrict__ W1, const float* __restrict__ b1,
    const float* __restrict__ W2, const float* __restrict__ b2,
    const float* __restrict__ ws_, float* __restrict__ out)
{
    const int b = blockIdx.x;
    const int tid = threadIdx.x;
    __shared__ float wx[HEADS][EMB];
    __shared__ float oh[EMB], op[EMB], hh[HALF];
    __shared__ float cf2[HEADS][12];
    if (tid < HEADS*12) ((float*)cf2)[tid] = ws_[WS_COEF2 + b*HEADS*12 + tid];
    __syncthreads();
    // assemble weighted_x
    for (int idx = tid; idx < HEADS*EMB; idx += 256) {
        const int h = idx >> 9, e = idx & 511;
        float val = bf[e];
        #pragma unroll
        for (int i = 0; i < IN_DIM; ++i) val += cf2[h][i]*Wf[i*EMB + e];
        if (e < HALF) {
            val += cf2[h][8]*Wl[e] + bl[e];
        } else {
            float s = 0.f;
            #pragma unroll
            for (int c = 0; c < 16; ++c)
                s += ws_[WS_SPART + ((b*16 + c)*HEADS + h)*HALF + (e - HALF)];
            val += s;
        }
        wx[h][e] = val;
    }
    __syncthreads();
    // oh[e] = wx[h(e)] . Wv[:,e] + bv[e]
    {
        const int e0 = tid, e1 = tid + 256;
        float a0 = bv[e0], a1 = bv[e1];
        const int h0 = e0 >> 6, h1i = e1 >> 6;
        #pragma unroll 4
        for (int j = 0; j < EMB; ++j) {
            a0 += wx[h0][j]*Wv[j*EMB + e0];
            a1 += wx[h1i][j]*Wv[j*EMB + e1];
        }
        oh[e0] = a0; oh[e1] = a1;
    }
    __syncthreads();
    // op = oh @ Wo + bo
    {
        const int e0 = tid, e1 = tid + 256;
        float a0 = bo[e0], a1 = bo[e1];
        #pragma unroll 4
        for (int j = 0; j < EMB; ++j) {
            const float x = oh[j];
            a0 += x*Wo[j*EMB + e0];
            a1 += x*Wo[j*EMB + e1];
        }
        op[e0] = a0; op[e1] = a1;
    }
    __syncthreads();
    // hh = relu(op @ W1 + b1)
    {
        float a = b1[tid];
        #pragma unroll 4
        for (int j = 0; j < EMB; ++j) a += op[j]*W1[j*HALF + tid];
        hh[tid] = fmaxf(a, 0.f);
    }
    __syncthreads();
    // logits = hh @ W2 + b2
    if (tid < NCLS) {
        float a = b2[tid];
        for (int m = 0; m < HALF; ++m) a += hh[m]*W2[m*NCLS + tid];
        out[b*NCLS + tid] = a;
    }
}

extern "C" void kernel_launch(void* const* d_in, const int* in_sizes, int n_in,
                              void* d_out, int out_size, void* d_ws, size_t ws_size,
                              hipStream_t stream)
{
    const float* feat = (const float*)d_in[0];
    const float* ts   = (const float*)d_in[1];
    const float* Wf = (const float*)d_in[2];
    const float* bf = (const float*)d_in[3];
    const float* Wl = (const float*)d_in[4];
    const float* bl = (const float*)d_in[5];
    const float* Wp = (const float*)d_in[6];
    const float* bp = (const float*)d_in[7];
    const float* Wq = (const float*)d_in[8];
    const float* bq = (const float*)d_in[9];
    const float* Wk = (const float*)d_in[10];
    const float* bk = (const float*)d_in[11];
    const float* Wv = (const float*)d_in[12];
    const float* bv = (const float*)d_in[13];
    const float* Wo = (const float*)d_in[14];
    const float* bo = (const float*)d_in[15];
    const float* td = (const float*)d_in[16];
    const float* W1 = (const float*)d_in[17];
    const float* b1 = (const float*)d_in[18];
    const float* W2 = (const float*)d_in[19];
    const float* b2 = (const float*)d_in[20];
    float* ws = (float*)d_ws;
    float* out = (float*)d_out;

    hipLaunchKernelGGL(k_prep,    dim3(B),      dim3(512), 0, stream,
                       feat, ts, Wf, bf, Wl, bl, Wp, bp, Wq, bq, Wk, bk, ws);
    hipLaunchKernelGGL(k_scores,  dim3(32, B),  dim3(256), 0, stream,
                       feat, ts, Wp, bp, td, ws);
    hipLaunchKernelGGL(k_softmax, dim3(B*HEADS),dim3(256), 0, stream,
                       feat, ts, ws);
    hipLaunchKernelGGL(k_sweight, dim3(16, B),  dim3(256), 0, stream,
                       ts, Wp, bp, ws);
    hipLaunchKernelGGL(k_final,   dim3(B),      dim3(256), 0, stream,
                       Wf, bf, Wl, bl, Wv, bv, Wo, bo, W1, b1, W2, b2, ws, out);
}

// Round 2
// 82.793 us; speedup vs baseline: 2.5911x; 2.5911x over previous
//
#include <hip/hip_runtime.h>
#include <hip/hip_bf16.h>
#include <math.h>

#define B 8
#define S 2048
#define IN_DIM 8
#define EMB 512
#define HEADS 8
#define HDIM 64
#define HALF 256
#define NCLS 3

// workspace layout (float offsets)
#define WS_KQ    0            // [B][HEADS][EMB]        = 32768
#define WS_COEF1 32768        // [B][HEADS][12]         = 768   (a[0..7], c0, c1)
#define WS_SC    33536        // [B][HEADS][S]          = 131072 (scores -> attn in place)
#define WS_COEF2 164608       // [B][HEADS][12]         = 768   (fa[0..7], ta)
#define WS_SPART 165376       // [B][16][HEADS][HALF]   = 262144
#define WS_Q     427520       // [B][EMB]               = 4096
#define WS_OH    431616       // [B][EMB]               = 4096
#define WS_OP    435712       // [B][EMB]               = 4096
// total 439808 floats = 1.76 MB

// K1: per-b: x_last -> q  (2-way split-K over j for q)
__global__ __launch_bounds__(1024) void k_prep(
    const float* __restrict__ feat, const float* __restrict__ ts,
    const float* __restrict__ Wf, const float* __restrict__ bf,
    const float* __restrict__ Wl, const float* __restrict__ bl,
    const float* __restrict__ Wp, const float* __restrict__ bp,
    const float* __restrict__ Wq, const float* __restrict__ bq,
    float* __restrict__ ws)
{
    const int b = blockIdx.x;
    const int tid = threadIdx.x;
    __shared__ float xl[EMB];
    __shared__ float qred[2][EMB];

    if (tid < EMB) {
        const float tl = ts[b*S + (S-1)];
        float acc = bf[tid];
        #pragma unroll
        for (int i = 0; i < IN_DIM; ++i)
            acc += feat[(b*S + (S-1))*IN_DIM + i] * Wf[i*EMB + tid];
        float te;
        if (tid < HALF) te = tl*Wl[tid] + bl[tid];
        else            te = __sinf(tl*Wp[tid-HALF] + bp[tid-HALF]);
        xl[tid] = acc + te;
    }
    __syncthreads();
    {
        const int e = tid & (EMB-1);
        const int jh = tid >> 9;           // 0..1
        float acc = (jh == 0) ? bq[e] : 0.f;
        #pragma unroll 8
        for (int j = jh*256; j < jh*256 + 256; ++j)
            acc += xl[j]*Wq[j*EMB + e];
        qred[jh][e] = acc;
    }
    __syncthreads();
    if (tid < EMB)
        ws[WS_Q + b*EMB + tid] = qred[0][tid] + qred[1][tid];
}

// K2: kq[b][h][j] = Wk[j, h*64:h*64+64] . q[h*64:h*64+64]
// one wave per head; coalesced 256B row-segment loads + wave reduce
__global__ __launch_bounds__(512) void k_kq(
    const float* __restrict__ Wk, float* __restrict__ ws)
{
    const int jc = blockIdx.x;     // 8 chunks x 64 j
    const int b  = blockIdx.y;
    const int h    = threadIdx.x >> 6;
    const int lane = threadIdx.x & 63;
    const float qv = ws[WS_Q + b*EMB + h*HDIM + lane];
    #pragma unroll 4
    for (int jj = 0; jj < 64; ++jj) {
        const int j = jc*64 + jj;
        float p = Wk[j*EMB + h*HDIM + lane]*qv;
        #pragma unroll
        for (int off = 32; off >= 1; off >>= 1) p += __shfl_xor(p, off, 64);
        if (lane == 0) ws[WS_KQ + (b*HEADS + h)*EMB + j] = p;
    }
}

// K3: per (b,h): a[i] = Wf[i,:].kq ; c0 = bf.kq + bl.kq_lo + q_h.bk_h ; c1 = Wl.kq_lo
__global__ __launch_bounds__(64) void k_coef(
    const float* __restrict__ Wf, const float* __restrict__ bf,
    const float* __restrict__ Wl, const float* __restrict__ bl,
    const float* __restrict__ bk, float* __restrict__ ws)
{
    const int bh = blockIdx.x;
    const int b = bh >> 3, h = bh & 7;
    const int lane = threadIdx.x;
    const float* kq = ws + WS_KQ + bh*EMB;

    float a[IN_DIM] = {0.f,0.f,0.f,0.f,0.f,0.f,0.f,0.f};
    float c0 = ws[WS_Q + b*EMB + h*HDIM + lane]*bk[h*HDIM + lane];
    float c1 = 0.f;
    #pragma unroll
    for (int e0 = 0; e0 < EMB; e0 += 64) {
        const int e = e0 + lane;
        const float kv = kq[e];
        #pragma unroll
        for (int i = 0; i < IN_DIM; ++i) a[i] += Wf[i*EMB + e]*kv;
        c0 += bf[e]*kv;
        if (e < HALF) { c0 += bl[e]*kv; c1 += Wl[e]*kv; }
    }
    #pragma unroll
    for (int off = 32; off >= 1; off >>= 1) {
        #pragma unroll
        for (int i = 0; i < IN_DIM; ++i) a[i] += __shfl_xor(a[i], off, 64);
        c0 += __shfl_xor(c0, off, 64);
        c1 += __shfl_xor(c1, off, 64);
    }
    if (lane == 0) {
        float* cp = ws + WS_COEF1 + bh*12;
        #pragma unroll
        for (int i = 0; i < IN_DIM; ++i) cp[i] = a[i];
        cp[8] = c0; cp[9] = c1;
    }
}

// K4: scores[b,h,t] = (f_t.a + c0 + t*c1 + sum_j sin(t*Wp[j]+bp[j])*kq_hi[h][j]) / 8 * decay
__global__ __launch_bounds__(256) void k_scores(
    const float* __restrict__ feat, const float* __restrict__ ts,
    const float* __restrict__ Wp, const float* __restrict__ bp,
    const float* __restrict__ tdp, float* __restrict__ ws)
{
    const int b = blockIdx.y;
    const int chunk = blockIdx.x;        // 32 chunks x 64 t
    const int tid = threadIdx.x;
    __shared__ __align__(16) float kqh[HEADS][HALF];
    __shared__ float wp_l[HALF], bp_l[HALF];
    __shared__ float cf[HEADS*12];

    for (int idx = tid; idx < HEADS*HALF; idx += 256) {
        const int h = idx >> 8, j = idx & 255;
        kqh[h][j] = ws[WS_KQ + (b*HEADS + h)*EMB + HALF + j];
    }
    if (tid < HALF) { wp_l[tid] = Wp[tid]; bp_l[tid] = bp[tid]; }
    if (tid < HEADS*12) cf[tid] = ws[WS_COEF1 + b*HEADS*12 + tid];
    __syncthreads();

    const int jq = tid & 3;                  // 4-way split over j
    const int t = chunk*64 + (tid >> 2);
    const float tv = ts[b*S + t];

    float acc[HEADS];
    #pragma unroll
    for (int h = 0; h < HEADS; ++h) acc[h] = 0.f;

    for (int jj = 0; jj < 64; jj += 4) {
        const int j0 = jq*64 + jj;
        const float s0 = __sinf(tv*wp_l[j0+0] + bp_l[j0+0]);
        const float s1 = __sinf(tv*wp_l[j0+1] + bp_l[j0+1]);
        const float s2 = __sinf(tv*wp_l[j0+2] + bp_l[j0+2]);
        const float s3 = __sinf(tv*wp_l[j0+3] + bp_l[j0+3]);
        #pragma unroll
        for (int h = 0; h < HEADS; ++h) {
            const float4 kv = *(const float4*)&kqh[h][j0];
            acc[h] += s0*kv.x + s1*kv.y + s2*kv.z + s3*kv.w;
        }
    }
    #pragma unroll
    for (int h = 0; h < HEADS; ++h) {
        acc[h] += __shfl_xor(acc[h], 1, 64);
        acc[h] += __shfl_xor(acc[h], 2, 64);
    }
    if (jq == 0) {
        const float tl = ts[b*S + (S-1)];
        const float dec = __expf(-tdp[0]*fabsf(tl - tv));
        float f[IN_DIM];
        #pragma unroll
        for (int i = 0; i < IN_DIM; ++i) f[i] = feat[(b*S + t)*IN_DIM + i];
        #pragma unroll
        for (int h = 0; h < HEADS; ++h) {
            const float* c = cf + h*12;
            float base = c[8] + tv*c[9];
            #pragma unroll
            for (int i = 0; i < IN_DIM; ++i) base += f[i]*c[i];
            ws[WS_SC + (b*HEADS + h)*S + t] = (base + acc[h])*0.125f*dec;
        }
    }
}

// K5: per (b,h): softmax over 2048 scores (in place) + fa[i]=sum attn*f, ta=sum attn*t
__global__ __launch_bounds__(256) void k_softmax(
    const float* __restrict__ feat, const float* __restrict__ ts,
    float* __restrict__ ws)
{
    const int bh = blockIdx.x;
    const int b = bh >> 3;
    const int tid = threadIdx.x;
    float* row = ws + WS_SC + bh*S;

    float v[8];
    float mx = -1e30f;
    #pragma unroll
    for (int i = 0; i < 8; ++i) { v[i] = row[tid + 256*i]; mx = fmaxf(mx, v[i]); }
    #pragma unroll
    for (int off = 32; off >= 1; off >>= 1) mx = fmaxf(mx, __shfl_xor(mx, off, 64));
    __shared__ float red[4];
    const int wid = tid >> 6, lane = tid & 63;
    if (lane == 0) red[wid] = mx;
    __syncthreads();
    mx = fmaxf(fmaxf(red[0], red[1]), fmaxf(red[2], red[3]));

    float sm = 0.f;
    #pragma unroll
    for (int i = 0; i < 8; ++i) { v[i] = __expf(v[i] - mx); sm += v[i]; }
    #pragma unroll
    for (int off = 32; off >= 1; off >>= 1) sm += __shfl_xor(sm, off, 64);
    __syncthreads();
    if (lane == 0) red[wid] = sm;
    __syncthreads();
    sm = red[0] + red[1] + red[2] + red[3];
    const float inv = 1.f/sm;

    float fa[IN_DIM] = {0.f,0.f,0.f,0.f,0.f,0.f,0.f,0.f};
    float ta = 0.f;
    #pragma unroll
    for (int i = 0; i < 8; ++i) {
        const int t = tid + 256*i;
        const float a_ = v[i]*inv;
        row[t] = a_;
        ta += a_*ts[b*S + t];
        const float4 f0 = *(const float4*)&feat[(b*S + t)*IN_DIM];
        const float4 f1 = *(const float4*)&feat[(b*S + t)*IN_DIM + 4];
        fa[0] += a_*f0.x; fa[1] += a_*f0.y; fa[2] += a_*f0.z; fa[3] += a_*f0.w;
        fa[4] += a_*f1.x; fa[5] += a_*f1.y; fa[6] += a_*f1.z; fa[7] += a_*f1.w;
    }
    #pragma unroll
    for (int off = 32; off >= 1; off >>= 1) {
        #pragma unroll
        for (int k = 0; k < IN_DIM; ++k) fa[k] += __shfl_xor(fa[k], off, 64);
        ta += __shfl_xor(ta, off, 64);
    }
    __shared__ float red9[4][12];
    if (lane == 0) {
        #pragma unroll
        for (int k = 0; k < IN_DIM; ++k) red9[wid][k] = fa[k];
        red9[wid][8] = ta;
    }
    __syncthreads();
    if (tid < 9) {
        const float sv = red9[0][tid]+red9[1][tid]+red9[2][tid]+red9[3][tid];
        ws[WS_COEF2 + bh*12 + tid] = sv;
    }
}

// K6: S_partial[b,chunk,h,j] = sum_{t in chunk} attn[b,h,t]*sin(t*Wp[j]+bp[j])
__global__ __launch_bounds__(256) void k_sweight(
    const float* __restrict__ ts, const float* __restrict__ Wp, const float* __restrict__ bp,
    float* __restrict__ ws)
{
    const int b = blockIdx.y;
    const int chunk = blockIdx.x;   // 16 chunks x 128 t
    const int tid = threadIdx.x;    // = j
    __shared__ __align__(16) float at_l[HEADS][128];
    __shared__ float tv_l[128];
    for (int idx = tid; idx < HEADS*128; idx += 256) {
        const int h = idx >> 7, tt = idx & 127;
        at_l[h][tt] = ws[WS_SC + (b*HEADS + h)*S + chunk*128 + tt];
    }
    if (tid < 128) tv_l[tid] = ts[b*S + chunk*128 + tid];
    __syncthreads();
    const float wj = Wp[tid], bj = bp[tid];
    float acc[HEADS] = {0.f,0.f,0.f,0.f,0.f,0.f,0.f,0.f};
    for (int tt = 0; tt < 128; tt += 4) {
        const float s0 = __sinf(tv_l[tt+0]*wj + bj);
        const float s1 = __sinf(tv_l[tt+1]*wj + bj);
        const float s2 = __sinf(tv_l[tt+2]*wj + bj);
        const float s3 = __sinf(tv_l[tt+3]*wj + bj);
        #pragma unroll
        for (int h = 0; h < HEADS; ++h) {
            const float4 av = *(const float4*)&at_l[h][tt];
            acc[h] += s0*av.x + s1*av.y + s2*av.z + s3*av.w;
        }
    }
    #pragma unroll
    for (int h = 0; h < HEADS; ++h)
        ws[WS_SPART + ((b*16 + chunk)*HEADS + h)*HALF + tid] = acc[h];
}

// K7: per (b,h): assemble wx[h] in LDS, then oh[b, h*64:h*64+64] = wx . Wv[:,cols] + bv
__global__ __launch_bounds__(256) void k_oh(
    const float* __restrict__ Wf, const float* __restrict__ bf,
    const float* __restrict__ Wl, const float* __restrict__ bl,
    const float* __restrict__ Wv, const float* __restrict__ bv,
    float* __restrict__ ws)
{
    const int h = blockIdx.x;
    const int b = blockIdx.y;
    const int tid = threadIdx.x;
    __shared__ float wx[EMB];
    __shared__ float cf[9];
    __shared__ float red[4][64];

    if (tid < 9) cf[tid] = ws[WS_COEF2 + (b*HEADS + h)*12 + tid];
    __syncthreads();
    #pragma unroll
    for (int r = 0; r < 2; ++r) {
        const int e = tid + r*256;
        float val = bf[e];
        #pragma unroll
        for (int i = 0; i < IN_DIM; ++i) val += cf[i]*Wf[i*EMB + e];
        if (r == 0) {
            val += cf[8]*Wl[e] + bl[e];
        } else {
            float s = 0.f;
            #pragma unroll
            for (int c = 0; c < 16; ++c)
                s += ws[WS_SPART + ((b*16 + c)*HEADS + h)*HALF + (e - HALF)];
            val += s;
        }
        wx[e] = val;
    }
    __syncthreads();
    {
        const int eo = tid & 63, jq = tid >> 6;
        const int e = h*HDIM + eo;
        float acc = 0.f;
        #pragma unroll 8
        for (int j = jq*128; j < jq*128 + 128; ++j)
            acc += wx[j]*Wv[j*EMB + e];
        red[jq][eo] = acc;
    }
    __syncthreads();
    if (tid < 64)
        ws[WS_OH + b*EMB + h*HDIM + tid] =
            red[0][tid]+red[1][tid]+red[2][tid]+red[3][tid] + bv[h*HDIM + tid];
}

// K8: generic 512->512 GEMV chunk: out[b, ec*64:+64] = x[b,:] . W[:,cols] + bias
__global__ __launch_bounds__(256) void k_gemv512(
    const float* __restrict__ W, const float* __restrict__ bias,
    float* __restrict__ ws, int in_off, int out_off)
{
    const int ec = blockIdx.x;
    const int b  = blockIdx.y;
    const int tid = threadIdx.x;
    __shared__ float xv[EMB];
    __shared__ float red[4][64];
    xv[tid]       = ws[in_off + b*EMB + tid];
    xv[tid + 256] = ws[in_off + b*EMB + tid + 256];
    __syncthreads();
    {
        const int eo = tid & 63, jq = tid >> 6;
        const int e = ec*64 + eo;
        float acc = 0.f;
        #pragma unroll 8
        for (int j = jq*128; j < jq*128 + 128; ++j)
            acc += xv[j]*W[j*EMB + e];
        red[jq][eo] = acc;
    }
    __syncthreads();
    if (tid < 64)
        ws[out_off + b*EMB + ec*64 + tid] =
            red[0][tid]+red[1][tid]+red[2][tid]+red[3][tid] + bias[ec*64 + tid];
}

// K9: per b: hh = relu(op @ W1 + b1) (4-way split-K), logits = hh @ W2 + b2
__global__ __launch_bounds__(1024) void k_tail(
    const float* __restrict__ W1, const float* __restrict__ b1,
    const float* __restrict__ W2, const float* __restrict__ b2,
    const float* __restrict__ ws, float* __restrict__ out)
{
    const int b = blockIdx.x;
    const int tid = threadIdx.x;
    __shared__ float xv[EMB];
    __shared__ float red[4][HALF];
    __shared__ float red3[4][3];

    if (tid < EMB) xv[tid] = ws[WS_OP + b*EMB + tid];
    __syncthreads();
    {
        const int m = tid & 255, jq = tid >> 8;
        float acc = 0.f;
        #pragma unroll 8
        for (int j = jq*128; j < jq*128 + 128; ++j)
            acc += xv[j]*W1[j*HALF + m];
        red[jq][m] = acc;
    }
    __syncthreads();
    if (tid < HALF) {
        const float hv = fmaxf(red[0][tid]+red[1][tid]+red[2][tid]+red[3][tid] + b1[tid], 0.f);
        float p0 = hv*W2[tid*NCLS + 0];
        float p1 = hv*W2[tid*NCLS + 1];
        float p2 = hv*W2[tid*NCLS + 2];
        #pragma unroll
        for (int off = 32; off >= 1; off >>= 1) {
            p0 += __shfl_xor(p0, off, 64);
            p1 += __shfl_xor(p1, off, 64);
            p2 += __shfl_xor(p2, off, 64);
        }
        const int wid = tid >> 6;
        if ((tid & 63) == 0) { red3[wid][0] = p0; red3[wid][1] = p1; red3[wid][2] = p2; }
    }
    __syncthreads();
    if (tid < NCLS)
        out[b*NCLS + tid] = red3[0][tid]+red3[1][tid]+red3[2][tid]+red3[3][tid] + b2[tid];
}

extern "C" void kernel_launch(void* const* d_in, const int* in_sizes, int n_in,
                              void* d_out, int out_size, void* d_ws, size_t ws_size,
                              hipStream_t stream)
{
    const float* feat = (const float*)d_in[0];
    const float* ts   = (const float*)d_in[1];
    const float* Wf = (const float*)d_in[2];
    const float* bf = (const float*)d_in[3];
    const float* Wl = (const float*)d_in[4];
    const float* bl = (const float*)d_in[5];
    const float* Wp = (const float*)d_in[6];
    const float* bp = (const float*)d_in[7];
    const float* Wq = (const float*)d_in[8];
    const float* bq = (const float*)d_in[9];
    const float* Wk = (const float*)d_in[10];
    const float* bk = (const float*)d_in[11];
    const float* Wv = (const float*)d_in[12];
    const float* bv = (const float*)d_in[13];
    const float* Wo = (const float*)d_in[14];
    const float* bo = (const float*)d_in[15];
    const float* td = (const float*)d_in[16];
    const float* W1 = (const float*)d_in[17];
    const float* b1 = (const float*)d_in[18];
    const float* W2 = (const float*)d_in[19];
    const float* b2 = (const float*)d_in[20];
    float* ws = (float*)d_ws;
    float* out = (float*)d_out;

    hipLaunchKernelGGL(k_prep,    dim3(B),       dim3(1024), 0, stream,
                       feat, ts, Wf, bf, Wl, bl, Wp, bp, Wq, bq, ws);
    hipLaunchKernelGGL(k_kq,      dim3(8, B),    dim3(512),  0, stream, Wk, ws);
    hipLaunchKernelGGL(k_coef,    dim3(B*HEADS), dim3(64),   0, stream,
                       Wf, bf, Wl, bl, bk, ws);
    hipLaunchKernelGGL(k_scores,  dim3(32, B),   dim3(256),  0, stream,
                       feat, ts, Wp, bp, td, ws);
    hipLaunchKernelGGL(k_softmax, dim3(B*HEADS), dim3(256),  0, stream,
                       feat, ts, ws);
    hipLaunchKernelGGL(k_sweight, dim3(16, B),   dim3(256),  0, stream,
                       ts, Wp, bp, ws);
    hipLaunchKernelGGL(k_oh,      dim3(HEADS, B),dim3(256),  0, stream,
                       Wf, bf, Wl, bl, Wv, bv, ws);
    hipLaunchKernelGGL(k_gemv512, dim3(8, B),    dim3(256),  0, stream,
                       Wo, bo, ws, WS_OH, WS_OP);
    hipLaunchKernelGGL(k_tail,    dim3(B),       dim3(1024), 0, stream,
                       W1, b1, W2, b2, ws, out);
}

// Round 3
// 56.782 us; speedup vs baseline: 3.7780x; 1.4581x over previous
//
#include <hip/hip_runtime.h>
#include <hip/hip_bf16.h>
#include <math.h>

#define B 8
#define S 2048
#define IN_DIM 8
#define EMB 512
#define HEADS 8
#define HDIM 64
#define HALF 256
#define NCLS 3

// workspace layout (float offsets)
#define WS_KQ    0            // [B][HEADS][EMB]        = 32768 (only hi half used downstream)
#define WS_COEF1 32768        // [B][HEADS][12]         = 768   (a[0..7], c0, c1)
#define WS_SC    33536        // [B][HEADS][S]          = 131072 (scores -> attn in place)
#define WS_COEF2 164608       // [B][HEADS][12]         = 768   (fa[0..7], ta)
#define WS_SPART 165376       // [B][16][HEADS][HALF]   = 262144
#define WS_OH    427520       // [B][EMB]               = 4096
#define WS_OP    431616       // [B][EMB]               = 4096

// K1: per (b,h): recompute x_last -> q-chunk(h) -> kq[b][h][0..511] -> coef
// One block per (b,h), 256 threads. No cross-lane reduce in the kq dot:
// one thread owns one (j) output, 16 float4 loads vs LDS q-chunk.
__global__ __launch_bounds__(256) void k_head(
    const float* __restrict__ feat, const float* __restrict__ ts,
    const float* __restrict__ Wf, const float* __restrict__ bf,
    const float* __restrict__ Wl, const float* __restrict__ bl,
    const float* __restrict__ Wp, const float* __restrict__ bp,
    const float* __restrict__ Wq, const float* __restrict__ bq,
    const float* __restrict__ Wk, const float* __restrict__ bk,
    float* __restrict__ ws)
{
    const int h = blockIdx.x;
    const int b = blockIdx.y;
    const int bh = b*HEADS + h;
    const int tid = threadIdx.x;
    __shared__ float xl[EMB];
    __shared__ __align__(16) float qc[HDIM];
    __shared__ float kq[EMB];
    __shared__ float red[4][64];
    __shared__ float red10[4][12];

    // phase 0: x at last position (all 512 elems)
    {
        const float tl = ts[b*S + (S-1)];
        float fv[IN_DIM];
        #pragma unroll
        for (int i = 0; i < IN_DIM; ++i) fv[i] = feat[(b*S + (S-1))*IN_DIM + i];
        #pragma unroll
        for (int r = 0; r < 2; ++r) {
            const int e = tid + r*256;
            float acc = bf[e];
            #pragma unroll
            for (int i = 0; i < IN_DIM; ++i) acc += fv[i]*Wf[i*EMB + e];
            if (r == 0) acc += tl*Wl[e] + bl[e];
            else        acc += __sinf(tl*Wp[e-HALF] + bp[e-HALF]);
            xl[e] = acc;
        }
    }
    __syncthreads();
    // phase 1: q-chunk for this head: qc[eo] = xl . Wq[:, h*64+eo] + bq, 4-way split-K
    {
        const int eo = tid & 63, jq = tid >> 6;
        float acc = (jq == 0) ? bq[h*HDIM + eo] : 0.f;
        #pragma unroll 8
        for (int j = jq*128; j < jq*128 + 128; ++j)
            acc += xl[j]*Wq[j*EMB + h*HDIM + eo];
        red[jq][eo] = acc;
    }
    __syncthreads();
    if (tid < HDIM) qc[tid] = red[0][tid]+red[1][tid]+red[2][tid]+red[3][tid];
    __syncthreads();
    // phase 2: kq[j] = Wk[j, h*64:+64] . qc   (one thread per j, float4 dot)
    {
        #pragma unroll
        for (int r = 0; r < 2; ++r) {
            const int j = tid + r*256;
            const float4* wr = (const float4*)(Wk + j*EMB + h*HDIM);
            const float4* qv = (const float4*)qc;
            float acc = 0.f;
            #pragma unroll
            for (int k = 0; k < 16; ++k) {
                const float4 w = wr[k], q4 = qv[k];
                acc += w.x*q4.x + w.y*q4.y + w.z*q4.z + w.w*q4.w;
            }
            kq[j] = acc;
            if (j >= HALF) ws[WS_KQ + bh*EMB + j] = acc;  // scores kernel reads hi half
        }
    }
    __syncthreads();
    // phase 3: coef: a[i] = Wf[i,:].kq ; c0 = bf.kq + bl.kq_lo + q_h.bk_h ; c1 = Wl.kq_lo
    {
        float a[IN_DIM] = {0.f,0.f,0.f,0.f,0.f,0.f,0.f,0.f};
        float c0 = 0.f, c1 = 0.f;
        #pragma unroll
        for (int r = 0; r < 2; ++r) {
            const int e = tid + r*256;
            const float kv = kq[e];
            #pragma unroll
            for (int i = 0; i < IN_DIM; ++i) a[i] += Wf[i*EMB + e]*kv;
            c0 += bf[e]*kv;
            if (r == 0) { c0 += bl[e]*kv; c1 += Wl[e]*kv; }
        }
        if (tid < HDIM) c0 += qc[tid]*bk[h*HDIM + tid];
        #pragma unroll
        for (int off = 32; off >= 1; off >>= 1) {
            #pragma unroll
            for (int i = 0; i < IN_DIM; ++i) a[i] += __shfl_xor(a[i], off, 64);
            c0 += __shfl_xor(c0, off, 64);
            c1 += __shfl_xor(c1, off, 64);
        }
        const int wid = tid >> 6, lane = tid & 63;
        if (lane == 0) {
            #pragma unroll
            for (int i = 0; i < IN_DIM; ++i) red10[wid][i] = a[i];
            red10[wid][8] = c0; red10[wid][9] = c1;
        }
        __syncthreads();
        if (tid < 10)
            ws[WS_COEF1 + bh*12 + tid] =
                red10[0][tid]+red10[1][tid]+red10[2][tid]+red10[3][tid];
    }
}

// K2: scores[b,h,t] = (f_t.a + c0 + t*c1 + sum_j sin(t*Wp[j]+bp[j])*kq_hi[h][j]) / 8 * decay
__global__ __launch_bounds__(256) void k_scores(
    const float* __restrict__ feat, const float* __restrict__ ts,
    const float* __restrict__ Wp, const float* __restrict__ bp,
    const float* __restrict__ tdp, float* __restrict__ ws)
{
    const int b = blockIdx.y;
    const int chunk = blockIdx.x;        // 32 chunks x 64 t
    const int tid = threadIdx.x;
    __shared__ __align__(16) float kqh[HEADS][HALF];
    __shared__ float wp_l[HALF], bp_l[HALF];
    __shared__ float cf[HEADS*12];

    for (int idx = tid; idx < HEADS*HALF; idx += 256) {
        const int h = idx >> 8, j = idx & 255;
        kqh[h][j] = ws[WS_KQ + (b*HEADS + h)*EMB + HALF + j];
    }
    if (tid < HALF) { wp_l[tid] = Wp[tid]; bp_l[tid] = bp[tid]; }
    if (tid < HEADS*12) cf[tid] = ws[WS_COEF1 + b*HEADS*12 + tid];
    __syncthreads();

    const int jq = tid & 3;                  // 4-way split over j
    const int t = chunk*64 + (tid >> 2);
    const float tv = ts[b*S + t];

    float acc[HEADS];
    #pragma unroll
    for (int h = 0; h < HEADS; ++h) acc[h] = 0.f;

    for (int jj = 0; jj < 64; jj += 4) {
        const int j0 = jq*64 + jj;
        const float s0 = __sinf(tv*wp_l[j0+0] + bp_l[j0+0]);
        const float s1 = __sinf(tv*wp_l[j0+1] + bp_l[j0+1]);
        const float s2 = __sinf(tv*wp_l[j0+2] + bp_l[j0+2]);
        const float s3 = __sinf(tv*wp_l[j0+3] + bp_l[j0+3]);
        #pragma unroll
        for (int h = 0; h < HEADS; ++h) {
            const float4 kv = *(const float4*)&kqh[h][j0];
            acc[h] += s0*kv.x + s1*kv.y + s2*kv.z + s3*kv.w;
        }
    }
    #pragma unroll
    for (int h = 0; h < HEADS; ++h) {
        acc[h] += __shfl_xor(acc[h], 1, 64);
        acc[h] += __shfl_xor(acc[h], 2, 64);
    }
    if (jq == 0) {
        const float tl = ts[b*S + (S-1)];
        const float dec = __expf(-tdp[0]*fabsf(tl - tv));
        float f[IN_DIM];
        #pragma unroll
        for (int i = 0; i < IN_DIM; ++i) f[i] = feat[(b*S + t)*IN_DIM + i];
        #pragma unroll
        for (int h = 0; h < HEADS; ++h) {
            const float* c = cf + h*12;
            float base = c[8] + tv*c[9];
            #pragma unroll
            for (int i = 0; i < IN_DIM; ++i) base += f[i]*c[i];
            ws[WS_SC + (b*HEADS + h)*S + t] = (base + acc[h])*0.125f*dec;
        }
    }
}

// K3: per (b,h): softmax over 2048 scores (in place) + fa[i]=sum attn*f, ta=sum attn*t
__global__ __launch_bounds__(256) void k_softmax(
    const float* __restrict__ feat, const float* __restrict__ ts,
    float* __restrict__ ws)
{
    const int bh = blockIdx.x;
    const int b = bh >> 3;
    const int tid = threadIdx.x;
    float* row = ws + WS_SC + bh*S;

    float v[8];
    float mx = -1e30f;
    #pragma unroll
    for (int i = 0; i < 8; ++i) { v[i] = row[tid + 256*i]; mx = fmaxf(mx, v[i]); }
    #pragma unroll
    for (int off = 32; off >= 1; off >>= 1) mx = fmaxf(mx, __shfl_xor(mx, off, 64));
    __shared__ float red[4];
    const int wid = tid >> 6, lane = tid & 63;
    if (lane == 0) red[wid] = mx;
    __syncthreads();
    mx = fmaxf(fmaxf(red[0], red[1]), fmaxf(red[2], red[3]));

    float sm = 0.f;
    #pragma unroll
    for (int i = 0; i < 8; ++i) { v[i] = __expf(v[i] - mx); sm += v[i]; }
    #pragma unroll
    for (int off = 32; off >= 1; off >>= 1) sm += __shfl_xor(sm, off, 64);
    __syncthreads();
    if (lane == 0) red[wid] = sm;
    __syncthreads();
    sm = red[0] + red[1] + red[2] + red[3];
    const float inv = 1.f/sm;

    float fa[IN_DIM] = {0.f,0.f,0.f,0.f,0.f,0.f,0.f,0.f};
    float ta = 0.f;
    #pragma unroll
    for (int i = 0; i < 8; ++i) {
        const int t = tid + 256*i;
        const float a_ = v[i]*inv;
        row[t] = a_;
        ta += a_*ts[b*S + t];
        const float4 f0 = *(const float4*)&feat[(b*S + t)*IN_DIM];
        const float4 f1 = *(const float4*)&feat[(b*S + t)*IN_DIM + 4];
        fa[0] += a_*f0.x; fa[1] += a_*f0.y; fa[2] += a_*f0.z; fa[3] += a_*f0.w;
        fa[4] += a_*f1.x; fa[5] += a_*f1.y; fa[6] += a_*f1.z; fa[7] += a_*f1.w;
    }
    #pragma unroll
    for (int off = 32; off >= 1; off >>= 1) {
        #pragma unroll
        for (int k = 0; k < IN_DIM; ++k) fa[k] += __shfl_xor(fa[k], off, 64);
        ta += __shfl_xor(ta, off, 64);
    }
    __shared__ float red9[4][12];
    if (lane == 0) {
        #pragma unroll
        for (int k = 0; k < IN_DIM; ++k) red9[wid][k] = fa[k];
        red9[wid][8] = ta;
    }
    __syncthreads();
    if (tid < 9) {
        const float sv = red9[0][tid]+red9[1][tid]+red9[2][tid]+red9[3][tid];
        ws[WS_COEF2 + bh*12 + tid] = sv;
    }
}

// K4: S_partial[b,chunk,h,j] = sum_{t in chunk} attn[b,h,t]*sin(t*Wp[j]+bp[j])
__global__ __launch_bounds__(256) void k_sweight(
    const float* __restrict__ ts, const float* __restrict__ Wp, const float* __restrict__ bp,
    float* __restrict__ ws)
{
    const int b = blockIdx.y;
    const int chunk = blockIdx.x;   // 16 chunks x 128 t
    const int tid = threadIdx.x;    // = j
    __shared__ __align__(16) float at_l[HEADS][128];
    __shared__ float tv_l[128];
    for (int idx = tid; idx < HEADS*128; idx += 256) {
        const int h = idx >> 7, tt = idx & 127;
        at_l[h][tt] = ws[WS_SC + (b*HEADS + h)*S + chunk*128 + tt];
    }
    if (tid < 128) tv_l[tid] = ts[b*S + chunk*128 + tid];
    __syncthreads();
    const float wj = Wp[tid], bj = bp[tid];
    float acc[HEADS] = {0.f,0.f,0.f,0.f,0.f,0.f,0.f,0.f};
    for (int tt = 0; tt < 128; tt += 4) {
        const float s0 = __sinf(tv_l[tt+0]*wj + bj);
        const float s1 = __sinf(tv_l[tt+1]*wj + bj);
        const float s2 = __sinf(tv_l[tt+2]*wj + bj);
        const float s3 = __sinf(tv_l[tt+3]*wj + bj);
        #pragma unroll
        for (int h = 0; h < HEADS; ++h) {
            const float4 av = *(const float4*)&at_l[h][tt];
            acc[h] += s0*av.x + s1*av.y + s2*av.z + s3*av.w;
        }
    }
    #pragma unroll
    for (int h = 0; h < HEADS; ++h)
        ws[WS_SPART + ((b*16 + chunk)*HEADS + h)*HALF + tid] = acc[h];
}

// K5: per (b,h): assemble wx[h] in LDS, then oh[b, h*64:h*64+64] = wx . Wv[:,cols] + bv
__global__ __launch_bounds__(256) void k_oh(
    const float* __restrict__ Wf, const float* __restrict__ bf,
    const float* __restrict__ Wl, const float* __restrict__ bl,
    const float* __restrict__ Wv, const float* __restrict__ bv,
    float* __restrict__ ws)
{
    const int h = blockIdx.x;
    const int b = blockIdx.y;
    const int tid = threadIdx.x;
    __shared__ float wx[EMB];
    __shared__ float cf[9];
    __shared__ float red[4][64];

    if (tid < 9) cf[tid] = ws[WS_COEF2 + (b*HEADS + h)*12 + tid];
    __syncthreads();
    #pragma unroll
    for (int r = 0; r < 2; ++r) {
        const int e = tid + r*256;
        float val = bf[e];
        #pragma unroll
        for (int i = 0; i < IN_DIM; ++i) val += cf[i]*Wf[i*EMB + e];
        if (r == 0) {
            val += cf[8]*Wl[e] + bl[e];
        } else {
            float s = 0.f;
            #pragma unroll
            for (int c = 0; c < 16; ++c)
                s += ws[WS_SPART + ((b*16 + c)*HEADS + h)*HALF + (e - HALF)];
            val += s;
        }
        wx[e] = val;
    }
    __syncthreads();
    {
        const int eo = tid & 63, jq = tid >> 6;
        const int e = h*HDIM + eo;
        float acc = 0.f;
        #pragma unroll 8
        for (int j = jq*128; j < jq*128 + 128; ++j)
            acc += wx[j]*Wv[j*EMB + e];
        red[jq][eo] = acc;
    }
    __syncthreads();
    if (tid < 64)
        ws[WS_OH + b*EMB + h*HDIM + tid] =
            red[0][tid]+red[1][tid]+red[2][tid]+red[3][tid] + bv[h*HDIM + tid];
}

// K6: generic 512->512 GEMV chunk: out[b, ec*64:+64] = x[b,:] . W[:,cols] + bias
__global__ __launch_bounds__(256) void k_gemv512(
    const float* __restrict__ W, const float* __restrict__ bias,
    float* __restrict__ ws, int in_off, int out_off)
{
    const int ec = blockIdx.x;
    const int b  = blockIdx.y;
    const int tid = threadIdx.x;
    __shared__ float xv[EMB];
    __shared__ float red[4][64];
    xv[tid]       = ws[in_off + b*EMB + tid];
    xv[tid + 256] = ws[in_off + b*EMB + tid + 256];
    __syncthreads();
    {
        const int eo = tid & 63, jq = tid >> 6;
        const int e = ec*64 + eo;
        float acc = 0.f;
        #pragma unroll 8
        for (int j = jq*128; j < jq*128 + 128; ++j)
            acc += xv[j]*W[j*EMB + e];
        red[jq][eo] = acc;
    }
    __syncthreads();
    if (tid < 64)
        ws[out_off + b*EMB + ec*64 + tid] =
            red[0][tid]+red[1][tid]+red[2][tid]+red[3][tid] + bias[ec*64 + tid];
}

// K7: per b: hh = relu(op @ W1 + b1) (4-way split-K), logits = hh @ W2 + b2
__global__ __launch_bounds__(1024) void k_tail(
    const float* __restrict__ W1, const float* __restrict__ b1,
    const float* __restrict__ W2, const float* __restrict__ b2,
    const float* __restrict__ ws, float* __restrict__ out)
{
    const int b = blockIdx.x;
    const int tid = threadIdx.x;
    __shared__ float xv[EMB];
    __shared__ float red[4][HALF];
    __shared__ float red3[4][3];

    if (tid < EMB) xv[tid] = ws[WS_OP + b*EMB + tid];
    __syncthreads();
    {
        const int m = tid & 255, jq = tid >> 8;
        float acc = 0.f;
        #pragma unroll 8
        for (int j = jq*128; j < jq*128 + 128; ++j)
            acc += xv[j]*W1[j*HALF + m];
        red[jq][m] = acc;
    }
    __syncthreads();
    if (tid < HALF) {
        const float hv = fmaxf(red[0][tid]+red[1][tid]+red[2][tid]+red[3][tid] + b1[tid], 0.f);
        float p0 = hv*W2[tid*NCLS + 0];
        float p1 = hv*W2[tid*NCLS + 1];
        float p2 = hv*W2[tid*NCLS + 2];
        #pragma unroll
        for (int off = 32; off >= 1; off >>= 1) {
            p0 += __shfl_xor(p0, off, 64);
            p1 += __shfl_xor(p1, off, 64);
            p2 += __shfl_xor(p2, off, 64);
        }
        const int wid = tid >> 6;
        if ((tid & 63) == 0) { red3[wid][0] = p0; red3[wid][1] = p1; red3[wid][2] = p2; }
    }
    __syncthreads();
    if (tid < NCLS)
        out[b*NCLS + tid] = red3[0][tid]+red3[1][tid]+red3[2][tid]+red3[3][tid] + b2[tid];
}

extern "C" void kernel_launch(void* const* d_in, const int* in_sizes, int n_in,
                              void* d_out, int out_size, void* d_ws, size_t ws_size,
                              hipStream_t stream)
{
    const float* feat = (const float*)d_in[0];
    const float* ts   = (const float*)d_in[1];
    const float* Wf = (const float*)d_in[2];
    const float* bf = (const float*)d_in[3];
    const float* Wl = (const float*)d_in[4];
    const float* bl = (const float*)d_in[5];
    const float* Wp = (const float*)d_in[6];
    const float* bp = (const float*)d_in[7];
    const float* Wq = (const float*)d_in[8];
    const float* bq = (const float*)d_in[9];
    const float* Wk = (const float*)d_in[10];
    const float* bk = (const float*)d_in[11];
    const float* Wv = (const float*)d_in[12];
    const float* bv = (const float*)d_in[13];
    const float* Wo = (const float*)d_in[14];
    const float* bo = (const float*)d_in[15];
    const float* td = (const float*)d_in[16];
    const float* W1 = (const float*)d_in[17];
    const float* b1 = (const float*)d_in[18];
    const float* W2 = (const float*)d_in[19];
    const float* b2 = (const float*)d_in[20];
    float* ws = (float*)d_ws;
    float* out = (float*)d_out;

    hipLaunchKernelGGL(k_head,    dim3(HEADS, B),dim3(256),  0, stream,
                       feat, ts, Wf, bf, Wl, bl, Wp, bp, Wq, bq, Wk, bk, ws);
    hipLaunchKernelGGL(k_scores,  dim3(32, B),   dim3(256),  0, stream,
                       feat, ts, Wp, bp, td, ws);
    hipLaunchKernelGGL(k_softmax, dim3(B*HEADS), dim3(256),  0, stream,
                       feat, ts, ws);
    hipLaunchKernelGGL(k_sweight, dim3(16, B),   dim3(256),  0, stream,
                       ts, Wp, bp, ws);
    hipLaunchKernelGGL(k_oh,      dim3(HEADS, B),dim3(256),  0, stream,
                       Wf, bf, Wl, bl, Wv, bv, ws);
    hipLaunchKernelGGL(k_gemv512, dim3(8, B),    dim3(256),  0, stream,
                       Wo, bo, ws, WS_OH, WS_OP);
    hipLaunchKernelGGL(k_tail,    dim3(B),       dim3(1024), 0, stream,
                       W1, b1, W2, b2, ws, out);
}

// Round 4
// 47.373 us; speedup vs baseline: 4.5284x; 1.1986x over previous
//
#include <hip/hip_runtime.h>
#include <hip/hip_bf16.h>
#include <math.h>

#define B 8
#define S 2048
#define IN_DIM 8
#define EMB 512
#define HEADS 8
#define HDIM 64
#define HALF 256
#define NCLS 3
#define NCHUNK 32   // t-chunks of 64

// workspace layout (float offsets)
#define WS_KQ    0            // [B][HEADS][EMB]   (hi half used)      = 32768
#define WS_COEF1 32768        // [B][HEADS][12]  (a[0..7], c0, c1)     = 768
#define WS_PM    33536        // [B][32][HEADS][16] (m,Z,ta,fa[8])     = 32768
#define WS_PS    66304        // [B][32][HEADS][256] S-partials        = 524288
#define WS_OH    590592       // [B][EMB]                              = 4096
#define WS_OP    594688       // [B][EMB]                              = 4096

// K1: per (b,h): recompute x_last -> q-chunk(h) -> kq[b][h][:] -> coef
__global__ __launch_bounds__(256) void k_head(
    const float* __restrict__ feat, const float* __restrict__ ts,
    const float* __restrict__ Wf, const float* __restrict__ bf,
    const float* __restrict__ Wl, const float* __restrict__ bl,
    const float* __restrict__ Wp, const float* __restrict__ bp,
    const float* __restrict__ Wq, const float* __restrict__ bq,
    const float* __restrict__ Wk, const float* __restrict__ bk,
    float* __restrict__ ws)
{
    const int h = blockIdx.x;
    const int b = blockIdx.y;
    const int bh = b*HEADS + h;
    const int tid = threadIdx.x;
    __shared__ float xl[EMB];
    __shared__ __align__(16) float qc[HDIM];
    __shared__ float kq[EMB];
    __shared__ float red[4][64];
    __shared__ float red10[4][12];

    // phase 0: x at last position
    {
        const float tl = ts[b*S + (S-1)];
        float fv[IN_DIM];
        #pragma unroll
        for (int i = 0; i < IN_DIM; ++i) fv[i] = feat[(b*S + (S-1))*IN_DIM + i];
        #pragma unroll
        for (int r = 0; r < 2; ++r) {
            const int e = tid + r*256;
            float acc = bf[e];
            #pragma unroll
            for (int i = 0; i < IN_DIM; ++i) acc += fv[i]*Wf[i*EMB + e];
            if (r == 0) acc += tl*Wl[e] + bl[e];
            else        acc += __sinf(tl*Wp[e-HALF] + bp[e-HALF]);
            xl[e] = acc;
        }
    }
    __syncthreads();
    // phase 1: q-chunk for this head (4-way split-K)
    {
        const int eo = tid & 63, jq = tid >> 6;
        float acc = (jq == 0) ? bq[h*HDIM + eo] : 0.f;
        #pragma unroll 8
        for (int j = jq*128; j < jq*128 + 128; ++j)
            acc += xl[j]*Wq[j*EMB + h*HDIM + eo];
        red[jq][eo] = acc;
    }
    __syncthreads();
    if (tid < HDIM) qc[tid] = red[0][tid]+red[1][tid]+red[2][tid]+red[3][tid];
    __syncthreads();
    // phase 2: kq[j] = Wk[j, h*64:+64] . qc
    {
        #pragma unroll
        for (int r = 0; r < 2; ++r) {
            const int j = tid + r*256;
            const float4* wr = (const float4*)(Wk + j*EMB + h*HDIM);
            const float4* qv = (const float4*)qc;
            float acc = 0.f;
            #pragma unroll
            for (int k = 0; k < 16; ++k) {
                const float4 w = wr[k], q4 = qv[k];
                acc += w.x*q4.x + w.y*q4.y + w.z*q4.z + w.w*q4.w;
            }
            kq[j] = acc;
            if (j >= HALF) ws[WS_KQ + bh*EMB + j] = acc;
        }
    }
    __syncthreads();
    // phase 3: coef
    {
        float a[IN_DIM] = {0.f,0.f,0.f,0.f,0.f,0.f,0.f,0.f};
        float c0 = 0.f, c1 = 0.f;
        #pragma unroll
        for (int r = 0; r < 2; ++r) {
            const int e = tid + r*256;
            const float kv = kq[e];
            #pragma unroll
            for (int i = 0; i < IN_DIM; ++i) a[i] += Wf[i*EMB + e]*kv;
            c0 += bf[e]*kv;
            if (r == 0) { c0 += bl[e]*kv; c1 += Wl[e]*kv; }
        }
        if (tid < HDIM) c0 += qc[tid]*bk[h*HDIM + tid];
        #pragma unroll
        for (int off = 32; off >= 1; off >>= 1) {
            #pragma unroll
            for (int i = 0; i < IN_DIM; ++i) a[i] += __shfl_xor(a[i], off, 64);
            c0 += __shfl_xor(c0, off, 64);
            c1 += __shfl_xor(c1, off, 64);
        }
        const int wid = tid >> 6, lane = tid & 63;
        if (lane == 0) {
            #pragma unroll
            for (int i = 0; i < IN_DIM; ++i) red10[wid][i] = a[i];
            red10[wid][8] = c0; red10[wid][9] = c1;
        }
        __syncthreads();
        if (tid < 10)
            ws[WS_COEF1 + bh*12 + tid] =
                red10[0][tid]+red10[1][tid]+red10[2][tid]+red10[3][tid];
    }
}

// K2: per (b, 64-t chunk): sin table once -> scores(8h) -> local softmax stats
//     -> unnormalized S-partials. Flash-style chunk partials.
__global__ __launch_bounds__(256) void k_part(
    const float* __restrict__ feat, const float* __restrict__ ts,
    const float* __restrict__ Wp, const float* __restrict__ bp,
    const float* __restrict__ tdp, float* __restrict__ ws)
{
    const int c = blockIdx.x;      // 0..31
    const int b = blockIdx.y;
    const int tid = threadIdx.x;   // 256
    const int t0 = c*64;

    __shared__ float sin_l[256*65];            // [j][t] stride 65 (bank-safe)
    __shared__ __align__(16) float kqh[HEADS][256];
    __shared__ __align__(16) float w_l[64*8];  // [t][h]
    __shared__ float tv_l[64];
    __shared__ float f_l[64*9];                // [t][i] stride 9
    __shared__ float cf[96];                   // [h][12]

    if (tid < 64) tv_l[tid] = ts[b*S + t0 + tid];
    for (int idx = tid; idx < 64*IN_DIM; idx += 256) {
        const int tt = idx >> 3, i = idx & 7;
        f_l[tt*9 + i] = feat[(b*S + t0 + tt)*IN_DIM + i];
    }
    for (int idx = tid; idx < HEADS*256; idx += 256)
        ((float*)kqh)[idx] = ws[WS_KQ + (b*HEADS + (idx >> 8))*EMB + HALF + (idx & 255)];
    if (tid < 96) cf[tid] = ws[WS_COEF1 + b*96 + tid];
    const float tl = ts[b*S + (S-1)];
    const float td = tdp[0];
    __syncthreads();

    // phase 1: sin table (each value computed once, used for scores AND S)
    {
        const float wj = Wp[tid], bj = bp[tid];
        float* srow = sin_l + tid*65;
        #pragma unroll 4
        for (int tt = 0; tt < 64; ++tt)
            srow[tt] = __sinf(tv_l[tt]*wj + bj);
    }
    __syncthreads();

    // phase 2: scores for (t, h0) and (t, h0+4)
    const int t = tid & 63, h0 = tid >> 6;
    const float tv = tv_l[t];
    float fv[IN_DIM];
    #pragma unroll
    for (int i = 0; i < IN_DIM; ++i) fv[i] = f_l[t*9 + i];
    const float dec = __expf(-td*fabsf(tl - tv));
    float sc[2];
    {
        float acc0 = 0.f, acc1 = 0.f;
        const float4* kq0 = (const float4*)&kqh[h0][0];
        const float4* kq1 = (const float4*)&kqh[h0+4][0];
        #pragma unroll 4
        for (int j4 = 0; j4 < 64; ++j4) {
            const float s0 = sin_l[(j4*4+0)*65 + t];
            const float s1 = sin_l[(j4*4+1)*65 + t];
            const float s2 = sin_l[(j4*4+2)*65 + t];
            const float s3 = sin_l[(j4*4+3)*65 + t];
            const float4 ka = kq0[j4], kb = kq1[j4];
            acc0 += s0*ka.x + s1*ka.y + s2*ka.z + s3*ka.w;
            acc1 += s0*kb.x + s1*kb.y + s2*kb.z + s3*kb.w;
        }
        #pragma unroll
        for (int p = 0; p < 2; ++p) {
            const int h = h0 + p*4;
            float base = cf[h*12+8] + tv*cf[h*12+9];
            #pragma unroll
            for (int i = 0; i < IN_DIM; ++i) base += fv[i]*cf[h*12+i];
            sc[p] = (base + ((p == 0) ? acc0 : acc1))*0.125f*dec;
        }
    }
    // phase 3: per-wave (= per (h,chunk)) local softmax stats
    #pragma unroll
    for (int p = 0; p < 2; ++p) {
        const int h = h0 + p*4;
        float m = sc[p];
        #pragma unroll
        for (int off = 32; off >= 1; off >>= 1) m = fmaxf(m, __shfl_xor(m, off, 64));
        const float w = __expf(sc[p] - m);
        float Z = w, ta = w*tv;
        float fa[IN_DIM];
        #pragma unroll
        for (int i = 0; i < IN_DIM; ++i) fa[i] = w*fv[i];
        #pragma unroll
        for (int off = 32; off >= 1; off >>= 1) {
            Z  += __shfl_xor(Z,  off, 64);
            ta += __shfl_xor(ta, off, 64);
            #pragma unroll
            for (int i = 0; i < IN_DIM; ++i) fa[i] += __shfl_xor(fa[i], off, 64);
        }
        w_l[t*8 + h] = w;
        if (t == 0) {
            float* pm = ws + WS_PM + ((b*NCHUNK + c)*HEADS + h)*16;
            pm[0] = m; pm[1] = Z; pm[2] = ta;
            #pragma unroll
            for (int i = 0; i < IN_DIM; ++i) pm[3+i] = fa[i];
        }
    }
    __syncthreads();
    // phase 4: S_c[h][j] = sum_t w[t][h] * sin[j][t]  (unnormalized)
    {
        const int j = tid;
        float accS[HEADS] = {0.f,0.f,0.f,0.f,0.f,0.f,0.f,0.f};
        const float4* wv4 = (const float4*)w_l;
        const float* scol = sin_l + j*65;
        #pragma unroll 4
        for (int tt = 0; tt < 64; ++tt) {
            const float sv = scol[tt];
            const float4 wa = wv4[tt*2], wb = wv4[tt*2+1];
            accS[0] += wa.x*sv; accS[1] += wa.y*sv; accS[2] += wa.z*sv; accS[3] += wa.w*sv;
            accS[4] += wb.x*sv; accS[5] += wb.y*sv; accS[6] += wb.z*sv; accS[7] += wb.w*sv;
        }
        const int base = WS_PS + ((b*NCHUNK + c)*HEADS)*256 + j;
        #pragma unroll
        for (int h = 0; h < HEADS; ++h) ws[base + h*256] = accS[h];
    }
}

// K3: per (b,h): combine chunk partials (flash merge) -> wx assembly -> Wv gemv
__global__ __launch_bounds__(256) void k_ohc(
    const float* __restrict__ Wf, const float* __restrict__ bf,
    const float* __restrict__ Wl, const float* __restrict__ bl,
    const float* __restrict__ Wv, const float* __restrict__ bv,
    const float* __restrict__ ws_, float* __restrict__ ws)
{
    const int h = blockIdx.x;
    const int b = blockIdx.y;
    const int tid = threadIdx.x;
    __shared__ float pm[NCHUNK][12];
    __shared__ float al[NCHUNK];
    __shared__ float cf[10];           // fa[0..7], ta, inv
    __shared__ float wx[EMB];
    __shared__ float red[4][64];

    for (int idx = tid; idx < NCHUNK*12; idx += 256) {
        const int c = idx / 12, k = idx % 12;
        pm[c][k] = (k < 11) ? ws_[WS_PM + ((b*NCHUNK + c)*HEADS + h)*16 + k] : 0.f;
    }
    __syncthreads();
    float m = pm[0][0];
    #pragma unroll 8
    for (int c = 1; c < NCHUNK; ++c) m = fmaxf(m, pm[c][0]);
    if (tid < NCHUNK) al[tid] = __expf(pm[tid][0] - m);
    __syncthreads();
    float Z = 0.f;
    #pragma unroll 8
    for (int c = 0; c < NCHUNK; ++c) Z += al[c]*pm[c][1];
    const float inv = 1.f/Z;
    if (tid < 9) {
        const int k = (tid == 8) ? 2 : 3 + tid;   // ta at [2], fa_i at [3+i]
        float acc = 0.f;
        #pragma unroll 8
        for (int c = 0; c < NCHUNK; ++c) acc += al[c]*pm[c][k];
        cf[(tid == 8) ? 8 : tid] = acc*inv;
    }
    __syncthreads();
    // S[j] + wx assembly
    {
        const int j = tid;
        float acc = 0.f;
        #pragma unroll 8
        for (int c = 0; c < NCHUNK; ++c)
            acc += al[c]*ws_[WS_PS + ((b*NCHUNK + c)*HEADS + h)*256 + j];
        float vh = bf[HALF + j] + acc*inv;
        float vl = bf[j] + cf[8]*Wl[j] + bl[j];
        #pragma unroll
        for (int i = 0; i < IN_DIM; ++i) {
            vh += cf[i]*Wf[i*EMB + HALF + j];
            vl += cf[i]*Wf[i*EMB + j];
        }
        wx[j] = vl;
        wx[HALF + j] = vh;
    }
    __syncthreads();
    // Wv gemv for this head's 64 output cols (4-way split-K)
    {
        const int eo = tid & 63, jq = tid >> 6;
        const int e = h*HDIM + eo;
        float acc = 0.f;
        #pragma unroll 8
        for (int j = jq*128; j < jq*128 + 128; ++j)
            acc += wx[j]*Wv[j*EMB + e];
        red[jq][eo] = acc;
    }
    __syncthreads();
    if (tid < 64)
        ws[WS_OH + b*EMB + h*HDIM + tid] =
            red[0][tid]+red[1][tid]+red[2][tid]+red[3][tid] + bv[h*HDIM + tid];
}

// K4: 512->512 GEMV chunk: out[b, ec*64:+64] = x[b,:] . W[:,cols] + bias
__global__ __launch_bounds__(256) void k_gemv512(
    const float* __restrict__ W, const float* __restrict__ bias,
    float* __restrict__ ws, int in_off, int out_off)
{
    const int ec = blockIdx.x;
    const int b  = blockIdx.y;
    const int tid = threadIdx.x;
    __shared__ float xv[EMB];
    __shared__ float red[4][64];
    xv[tid]       = ws[in_off + b*EMB + tid];
    xv[tid + 256] = ws[in_off + b*EMB + tid + 256];
    __syncthreads();
    {
        const int eo = tid & 63, jq = tid >> 6;
        const int e = ec*64 + eo;
        float acc = 0.f;
        #pragma unroll 8
        for (int j = jq*128; j < jq*128 + 128; ++j)
            acc += xv[j]*W[j*EMB + e];
        red[jq][eo] = acc;
    }
    __syncthreads();
    if (tid < 64)
        ws[out_off + b*EMB + ec*64 + tid] =
            red[0][tid]+red[1][tid]+red[2][tid]+red[3][tid] + bias[ec*64 + tid];
}

// K5: per b: hh = relu(op @ W1 + b1), logits = hh @ W2 + b2
__global__ __launch_bounds__(1024) void k_tail(
    const float* __restrict__ W1, const float* __restrict__ b1,
    const float* __restrict__ W2, const float* __restrict__ b2,
    const float* __restrict__ ws, float* __restrict__ out)
{
    const int b = blockIdx.x;
    const int tid = threadIdx.x;
    __shared__ float xv[EMB];
    __shared__ float red[4][HALF];
    __shared__ float red3[4][3];

    if (tid < EMB) xv[tid] = ws[WS_OP + b*EMB + tid];
    __syncthreads();
    {
        const int mm = tid & 255, jq = tid >> 8;
        float acc = 0.f;
        #pragma unroll 8
        for (int j = jq*128; j < jq*128 + 128; ++j)
            acc += xv[j]*W1[j*HALF + mm];
        red[jq][mm] = acc;
    }
    __syncthreads();
    if (tid < HALF) {
        const float hv = fmaxf(red[0][tid]+red[1][tid]+red[2][tid]+red[3][tid] + b1[tid], 0.f);
        float p0 = hv*W2[tid*NCLS + 0];
        float p1 = hv*W2[tid*NCLS + 1];
        float p2 = hv*W2[tid*NCLS + 2];
        #pragma unroll
        for (int off = 32; off >= 1; off >>= 1) {
            p0 += __shfl_xor(p0, off, 64);
            p1 += __shfl_xor(p1, off, 64);
            p2 += __shfl_xor(p2, off, 64);
        }
        const int wid = tid >> 6;
        if ((tid & 63) == 0) { red3[wid][0] = p0; red3[wid][1] = p1; red3[wid][2] = p2; }
    }
    __syncthreads();
    if (tid < NCLS)
        out[b*NCLS + tid] = red3[0][tid]+red3[1][tid]+red3[2][tid]+red3[3][tid] + b2[tid];
}

extern "C" void kernel_launch(void* const* d_in, const int* in_sizes, int n_in,
                              void* d_out, int out_size, void* d_ws, size_t ws_size,
                              hipStream_t stream)
{
    const float* feat = (const float*)d_in[0];
    const float* ts   = (const float*)d_in[1];
    const float* Wf = (const float*)d_in[2];
    const float* bf = (const float*)d_in[3];
    const float* Wl = (const float*)d_in[4];
    const float* bl = (const float*)d_in[5];
    const float* Wp = (const float*)d_in[6];
    const float* bp = (const float*)d_in[7];
    const float* Wq = (const float*)d_in[8];
    const float* bq = (const float*)d_in[9];
    const float* Wk = (const float*)d_in[10];
    const float* bk = (const float*)d_in[11];
    const float* Wv = (const float*)d_in[12];
    const float* bv = (const float*)d_in[13];
    const float* Wo = (const float*)d_in[14];
    const float* bo = (const float*)d_in[15];
    const float* td = (const float*)d_in[16];
    const float* W1 = (const float*)d_in[17];
    const float* b1 = (const float*)d_in[18];
    const float* W2 = (const float*)d_in[19];
    const float* b2 = (const float*)d_in[20];
    float* ws = (float*)d_ws;
    float* out = (float*)d_out;

    hipLaunchKernelGGL(k_head,    dim3(HEADS, B), dim3(256),  0, stream,
                       feat, ts, Wf, bf, Wl, bl, Wp, bp, Wq, bq, Wk, bk, ws);
    hipLaunchKernelGGL(k_part,    dim3(NCHUNK, B),dim3(256),  0, stream,
                       feat, ts, Wp, bp, td, ws);
    hipLaunchKernelGGL(k_ohc,     dim3(HEADS, B), dim3(256),  0, stream,
                       Wf, bf, Wl, bl, Wv, bv, ws, ws);
    hipLaunchKernelGGL(k_gemv512, dim3(8, B),     dim3(256),  0, stream,
                       Wo, bo, ws, WS_OH, WS_OP);
    hipLaunchKernelGGL(k_tail,    dim3(B),        dim3(1024), 0, stream,
                       W1, b1, W2, b2, ws, out);
}